// Round 4
// baseline (462.985 us; speedup 1.0000x reference)
//
#include <hip/hip_runtime.h>
#include <hip/hip_bf16.h>
#include <math.h>

typedef __bf16 bf16;
typedef __bf16 bf16x4 __attribute__((ext_vector_type(4)));
typedef __bf16 bf16x8 __attribute__((ext_vector_type(8)));
typedef float f32x4 __attribute__((ext_vector_type(4)));

#define NB 2
#define LSEQ 2048
#define NH 32
#define NKVH 8
#define HD 64
#define DMODEL 2048
#define CONVD 3072
#define NPROJ 5152
#define NPADN 5248
#define NCHUNK 16
#define CHUNK 128
#define ROWS 4096
#define EPSF 1e-5f

__device__ __forceinline__ float fsilu(float x) { return x / (1.0f + __expf(-x)); }

__device__ __forceinline__ void gld_lds16(const void* g, void* l) {
  __builtin_amdgcn_global_load_lds(
      (const __attribute__((address_space(1))) void*)g,
      (__attribute__((address_space(3))) void*)l, 16, 0, 0);
}

// xor-chunk swizzles: permute 8-element (16 B) chunks within a row so that
// row-major tiles with 128B/256B row stride read conflict-free in MFMA
// fragment patterns (16 rows/quad -> 8 distinct bank groups x2 = free).
__device__ __forceinline__ int swz64(int row, int col) {
  return row * 64 + ((((col >> 3) ^ row) & 7) << 3) + (col & 7);
}
__device__ __forceinline__ int swz128(int row, int col) {
  return row * 128 + (((col >> 3) ^ (row & 7)) << 3) + (col & 7);
}

// ---------------- fused casts: hs, W1 (zero-padded to NPADN rows), Wo ----------------
__global__ __launch_bounds__(256) void cast_all_kernel(
    const float* __restrict__ hs, const float* __restrict__ w1, const float* __restrict__ wo,
    bf16* __restrict__ hs_b, bf16* __restrict__ w1_b, bf16* __restrict__ wo_b) {
  const long n1 = (long)ROWS * DMODEL / 4;
  const long n2 = (long)NPADN * DMODEL / 4;
  const long n3 = (long)DMODEL * DMODEL / 4;
  long total = n1 + n2 + n3;
  long stride = (long)gridDim.x * blockDim.x;
  for (long i = blockIdx.x * (long)blockDim.x + threadIdx.x; i < total; i += stride) {
    if (i < n1) {
      float4 v = ((const float4*)hs)[i];
      bf16x4 o = {(bf16)v.x, (bf16)v.y, (bf16)v.z, (bf16)v.w};
      ((bf16x4*)hs_b)[i] = o;
    } else if (i < n1 + n2) {
      long j = i - n1;
      int n = (int)((j * 4) >> 11);  // row of W1 (2048 cols)
      bf16x4 o = {};
      if (n < NPROJ) {
        float4 v = ((const float4*)w1)[j];
        o = bf16x4{(bf16)v.x, (bf16)v.y, (bf16)v.z, (bf16)v.w};
      }
      ((bf16x4*)w1_b)[j] = o;
    } else {
      long j = i - n1 - n2;
      float4 v = ((const float4*)wo)[j];
      ((bf16x4*)wo_b)[j] = bf16x4{(bf16)v.x, (bf16)v.y, (bf16)v.z, (bf16)v.w};
    }
  }
}

// ---------------- GEMM: C[M,N] = A[M,K] * B[N,K]^T (bf16 in, OutT out) ----------------
template <typename OutT>
__global__ __launch_bounds__(256) void gemm_bt_kernel(
    const bf16* __restrict__ A, const bf16* __restrict__ B, OutT* __restrict__ C,
    int M, int N, int K, int ntx) {
  __shared__ __align__(16) bf16 As[128 * 64];
  __shared__ __align__(16) bf16 Bs[128 * 64];
  const int tid = threadIdx.x;
  const int lane = tid & 63;
  const int wave = tid >> 6;
  const int wm = wave >> 1, wn = wave & 1;

  const int GM = 8;
  int lid = blockIdx.x;
  int group = GM * ntx;
  int gid = lid / group;
  int rem = lid - gid * group;
  int bm = gid * GM + (rem % GM);
  int bn = rem / GM;

  f32x4 acc[4][4] = {};

  const bf16* Ab = A + (long)bm * 128 * K;
  const bf16* Bb = B + (long)bn * 128 * K;

  const int colsw = (((lane & 7) ^ ((lane >> 3) & 7)) << 3);
  const int fbA = (wm * 64 + (lane & 15)) * 64 + ((((lane >> 4) ^ (lane & 7))) << 3);
  const int fbB = (wn * 64 + (lane & 15)) * 64 + ((((lane >> 4) ^ (lane & 7))) << 3);

  for (int k0 = 0; k0 < K; k0 += 64) {
#pragma unroll
    for (int j = 0; j < 4; ++j) {
      int q = wave * 4 + j;
      int e = q * 512 + lane * 8;
      int row = q * 8 + (lane >> 3);
      gld_lds16((const void*)(Ab + (long)row * K + k0 + colsw), (void*)(As + e));
      gld_lds16((const void*)(Bb + (long)row * K + k0 + colsw), (void*)(Bs + e));
    }
    __syncthreads();
#pragma unroll
    for (int ks2 = 0; ks2 < 2; ++ks2) {
      bf16x8 af[4], bfb[4];
#pragma unroll
      for (int mi = 0; mi < 4; ++mi)
        af[mi] = *(const bf16x8*)(As + ((fbA + mi * 1024) ^ (ks2 << 5)));
#pragma unroll
      for (int ni = 0; ni < 4; ++ni)
        bfb[ni] = *(const bf16x8*)(Bs + ((fbB + ni * 1024) ^ (ks2 << 5)));
#pragma unroll
      for (int mi = 0; mi < 4; ++mi)
#pragma unroll
        for (int ni = 0; ni < 4; ++ni)
          acc[mi][ni] = __builtin_amdgcn_mfma_f32_16x16x32_bf16(af[mi], bfb[ni], acc[mi][ni], 0, 0, 0);
    }
    __syncthreads();
  }

#pragma unroll
  for (int mi = 0; mi < 4; ++mi) {
    int rbase = bm * 128 + wm * 64 + mi * 16 + (lane >> 4) * 4;
#pragma unroll
    for (int ni = 0; ni < 4; ++ni) {
      int col = bn * 128 + wn * 64 + ni * 16 + (lane & 15);
#pragma unroll
      for (int r = 0; r < 4; ++r)
        C[(long)(rbase + r) * N + col] = (OutT)acc[mi][ni][r];
    }
  }
}

// inclusive scan of 128 values in LDS (all 256 threads must call)
__device__ __forceinline__ void scan128(float* a, int tid) {
#pragma unroll
  for (int off = 1; off < CHUNK; off <<= 1) {
    float add = 0.f;
    if (tid >= off && tid < CHUNK) add = a[tid - off];
    __syncthreads();
    if (tid >= off && tid < CHUNK) a[tid] += add;
    __syncthreads();
  }
}

// softplus(raw + bias)
__device__ __forceinline__ float fsoftplus(float raw) {
  return (raw > 20.0f) ? raw : log1pf(__expf(raw));
}

// ---------------- SSD phase A (MFMA, conv fused): per-chunk states S[p][n] ----------------
__global__ __launch_bounds__(256) void ssd_states_kernel(
    const bf16* __restrict__ proj, const float* __restrict__ conv_w,
    const float* __restrict__ conv_b, const float* __restrict__ dt_bias,
    const float* __restrict__ A_log, float* __restrict__ states, float* __restrict__ asum) {
  __shared__ __align__(16) bf16 Xt[64 * 136];
  __shared__ __align__(16) bf16 Kwt[64 * 136];
  __shared__ float acs[CHUNK];
  __shared__ float dts[CHUNK];
  int bid = blockIdx.x;                       // ((b*16 + c)*32 + h)
  int h = bid & 31, c = (bid >> 5) & 15, b = bid >> 9;
  int kvh = h >> 2;
  int tid = threadIdx.x;
  int lane = tid & 63, wave = tid >> 6;
  long rowbase = (long)b * LSEQ + c * CHUNK;
  if (tid < CHUNK) {
    float raw = (float)proj[(rowbase + tid) * NPADN + (CONVD + DMODEL) + h] + dt_bias[h];
    float dtv = fsoftplus(raw);
    dts[tid] = dtv;
    acs[tid] = -__expf(A_log[h]) * dtv;
  }
  __syncthreads();
  scan128(acs, tid);
  float atot = acs[CHUNK - 1];
  for (int e = tid; e < CHUNK * HD; e += 256) {
    int j = e >> 6, p = e & 63;
    const bf16* cur = proj + (rowbase + j) * NPADN;
    bool hp = (c > 0) || (j > 0);
    int chk = 512 + kvh * HD + p;
    int chv = kvh * HD + p;
    float pk = hp ? (float)cur[chk - NPADN] : 0.f;
    float pv = hp ? (float)cur[chv - NPADN] : 0.f;
    float kc = fsilu(pk * conv_w[chk * 2] + (float)cur[chk] * conv_w[chk * 2 + 1] + conv_b[chk]);
    float xc = fsilu(pv * conv_w[chv * 2] + (float)cur[chv] * conv_w[chv * 2 + 1] + conv_b[chv]);
    Kwt[p * 136 + j] = (bf16)(kc * __expf(atot - acs[j]));
    Xt[p * 136 + j] = (bf16)(xc * dts[j]);
  }
  __syncthreads();

  f32x4 sacc[4] = {};
#pragma unroll
  for (int ks = 0; ks < CHUNK; ks += 32) {
    bf16x8 af = *(const bf16x8*)(Xt + (wave * 16 + (lane & 15)) * 136 + ks + (lane >> 4) * 8);
    bf16x8 bf_[4];
#pragma unroll
    for (int ni = 0; ni < 4; ++ni)
      bf_[ni] = *(const bf16x8*)(Kwt + (ni * 16 + (lane & 15)) * 136 + ks + (lane >> 4) * 8);
#pragma unroll
    for (int ni = 0; ni < 4; ++ni)
      sacc[ni] = __builtin_amdgcn_mfma_f32_16x16x32_bf16(af, bf_[ni], sacc[ni], 0, 0, 0);
  }
  float* sout = states + (long)bid * (HD * HD);
#pragma unroll
  for (int ni = 0; ni < 4; ++ni) {
    int n = ni * 16 + (lane & 15);
#pragma unroll
    for (int r = 0; r < 4; ++r) {
      int p = wave * 16 + (lane >> 4) * 4 + r;
      sout[p * HD + n] = sacc[ni][r];
    }
  }
  if (tid == 0) asum[(b * NH + h) * NCHUNK + c] = atot;
}

// ---------------- SSD phase B: inter-chunk state scan ----------------
__global__ __launch_bounds__(256) void ssd_scan_kernel(
    const float* __restrict__ states, const float* __restrict__ asum,
    float* __restrict__ sprev) {
  int bid = blockIdx.x;                       // b*256 + h*8 + s
  int s = bid & 7, h = (bid >> 3) & 31, b = bid >> 8;
  int e0 = s * 512 + threadIdx.x;
  int e1 = e0 + 256;
  float S0 = 0.f, S1 = 0.f;
  const float* as = asum + (b * NH + h) * NCHUNK;
  for (int c = 0; c < NCHUNK; ++c) {
    long off = ((long)((b * NCHUNK + c) * NH + h)) * (HD * HD);
    float g = __expf(as[c]);
    sprev[off + e0] = S0;
    sprev[off + e1] = S1;
    S0 = S0 * g + states[off + e0];
    S1 = S1 * g + states[off + e1];
  }
}

// ---------------- SSD phase C (MFMA, conv+gate fused): Yd + Yo + RMSNorm + gate ----------------
// LDS 74.5 KB -> 2 blocks/CU (xor-swizzled unpadded tiles)
__global__ __launch_bounds__(256) void ssd_out_kernel(
    const bf16* __restrict__ proj, const float* __restrict__ conv_w,
    const float* __restrict__ conv_b, const float* __restrict__ dt_bias,
    const float* __restrict__ A_log, const float* __restrict__ sprev,
    const float* __restrict__ gnw, bf16* __restrict__ yg) {
  __shared__ __align__(16) bf16 Cq[128 * 64];
  __shared__ __align__(16) bf16 BmXt[128 * 64];  // Bm [j][n] swz64; later Xt [p][j] swz128
  __shared__ __align__(16) bf16 G[128 * 128];    // [i][j] swz128
  __shared__ __align__(16) bf16 Sp[64 * 64];     // [p][n] swz64
  __shared__ float acs[CHUNK];
  __shared__ float dts[CHUNK];
  __shared__ float part[CHUNK][2];
  __shared__ float rs_l[CHUNK];

  int bid = blockIdx.x;                       // ((b*16 + c)*32 + h)
  int h = bid & 31, c = (bid >> 5) & 15, b = bid >> 9;
  int kvh = h >> 2;
  int tid = threadIdx.x;
  int lane = tid & 63, wave = tid >> 6;
  int wm = wave >> 1, wn = wave & 1;
  long rowbase = (long)b * LSEQ + c * CHUNK;

  if (tid < CHUNK) {
    float raw = (float)proj[(rowbase + tid) * NPADN + (CONVD + DMODEL) + h] + dt_bias[h];
    float dtv = fsoftplus(raw);
    dts[tid] = dtv;
    acs[tid] = -__expf(A_log[h]) * dtv;
  }
  // stage Cq = conv(q), Bm = conv(k)
  for (int e = tid; e < CHUNK * HD; e += 256) {
    int j = e >> 6, p = e & 63;
    const bf16* cur = proj + (rowbase + j) * NPADN;
    bool hp = (c > 0) || (j > 0);
    int chq = 1024 + h * HD + p;
    int chk = 512 + kvh * HD + p;
    float pq = hp ? (float)cur[chq - NPADN] : 0.f;
    float pk = hp ? (float)cur[chk - NPADN] : 0.f;
    float qc = fsilu(pq * conv_w[chq * 2] + (float)cur[chq] * conv_w[chq * 2 + 1] + conv_b[chq]);
    float kc = fsilu(pk * conv_w[chk * 2] + (float)cur[chk] * conv_w[chk * 2 + 1] + conv_b[chk]);
    Cq[swz64(j, p)] = (bf16)qc;
    BmXt[swz64(j, p)] = (bf16)kc;
  }
  {
    long soff = ((long)((b * NCHUNK + c) * NH + h)) * (HD * HD);
    for (int e = tid; e < HD * HD; e += 256) Sp[swz64(e >> 6, e & 63)] = (bf16)sprev[soff + e];
  }
  __syncthreads();
  scan128(acs, tid);

  // --- G = Cq . Bm^T  (128x128, K=64) ---
  {
    f32x4 gacc[4][4] = {};
#pragma unroll
    for (int ks = 0; ks < HD; ks += 32) {
      bf16x8 af[4], bf_[4];
#pragma unroll
      for (int mi = 0; mi < 4; ++mi)
        af[mi] = *(const bf16x8*)(Cq + swz64(wm * 64 + mi * 16 + (lane & 15), ks + (lane >> 4) * 8));
#pragma unroll
      for (int ni = 0; ni < 4; ++ni)
        bf_[ni] = *(const bf16x8*)(BmXt + swz64(wn * 64 + ni * 16 + (lane & 15), ks + (lane >> 4) * 8));
#pragma unroll
      for (int mi = 0; mi < 4; ++mi)
#pragma unroll
        for (int ni = 0; ni < 4; ++ni)
          gacc[mi][ni] = __builtin_amdgcn_mfma_f32_16x16x32_bf16(af[mi], bf_[ni], gacc[mi][ni], 0, 0, 0);
    }
#pragma unroll
    for (int mi = 0; mi < 4; ++mi) {
#pragma unroll
      for (int r = 0; r < 4; ++r) {
        int i = wm * 64 + mi * 16 + (lane >> 4) * 4 + r;
        float ai = acs[i];
#pragma unroll
        for (int ni = 0; ni < 4; ++ni) {
          int j = wn * 64 + ni * 16 + (lane & 15);
          float gv = (j <= i) ? gacc[mi][ni][r] * __expf(ai - acs[j]) : 0.f;
          G[swz128(i, j)] = (bf16)gv;
        }
      }
    }
  }
  __syncthreads();

  // --- overwrite BmXt with Xt[p][j] = conv(v)[j][p] * dt[j] ---
  for (int e = tid; e < CHUNK * HD; e += 256) {
    int j = e >> 6, p = e & 63;
    const bf16* cur = proj + (rowbase + j) * NPADN;
    bool hp = (c > 0) || (j > 0);
    int chv = kvh * HD + p;
    float pv = hp ? (float)cur[chv - NPADN] : 0.f;
    float xc = fsilu(pv * conv_w[chv * 2] + (float)cur[chv] * conv_w[chv * 2 + 1] + conv_b[chv]);
    BmXt[swz128(p, j)] = (bf16)(xc * dts[j]);
  }
  __syncthreads();

  // --- Yd = G . Xt^T (K=128); Yo = Cq . Sp^T (K=64) ---
  f32x4 yacc[4][2] = {};
  f32x4 oacc[4][2] = {};
#pragma unroll
  for (int ks = 0; ks < CHUNK; ks += 32) {
    bf16x8 af[4], bf_[2];
#pragma unroll
    for (int mi = 0; mi < 4; ++mi)
      af[mi] = *(const bf16x8*)(G + swz128(wm * 64 + mi * 16 + (lane & 15), ks + (lane >> 4) * 8));
#pragma unroll
    for (int ni = 0; ni < 2; ++ni)
      bf_[ni] = *(const bf16x8*)(BmXt + swz128(wn * 32 + ni * 16 + (lane & 15), ks + (lane >> 4) * 8));
#pragma unroll
    for (int mi = 0; mi < 4; ++mi)
#pragma unroll
      for (int ni = 0; ni < 2; ++ni)
        yacc[mi][ni] = __builtin_amdgcn_mfma_f32_16x16x32_bf16(af[mi], bf_[ni], yacc[mi][ni], 0, 0, 0);
  }
#pragma unroll
  for (int ks = 0; ks < HD; ks += 32) {
    bf16x8 af[4], bf_[2];
#pragma unroll
    for (int mi = 0; mi < 4; ++mi)
      af[mi] = *(const bf16x8*)(Cq + swz64(wm * 64 + mi * 16 + (lane & 15), ks + (lane >> 4) * 8));
#pragma unroll
    for (int ni = 0; ni < 2; ++ni)
      bf_[ni] = *(const bf16x8*)(Sp + swz64(wn * 32 + ni * 16 + (lane & 15), ks + (lane >> 4) * 8));
#pragma unroll
    for (int mi = 0; mi < 4; ++mi)
#pragma unroll
      for (int ni = 0; ni < 2; ++ni)
        oacc[mi][ni] = __builtin_amdgcn_mfma_f32_16x16x32_bf16(af[mi], bf_[ni], oacc[mi][ni], 0, 0, 0);
  }

  // --- combine, RMSNorm partials ---
  float yv[4][2][4];
#pragma unroll
  for (int mi = 0; mi < 4; ++mi) {
#pragma unroll
    for (int r = 0; r < 4; ++r) {
      int i = wm * 64 + mi * 16 + (lane >> 4) * 4 + r;
      float ei = __expf(acs[i]);
      float s = 0.f;
#pragma unroll
      for (int ni = 0; ni < 2; ++ni) {
        float v = yacc[mi][ni][r] + ei * oacc[mi][ni][r];
        yv[mi][ni][r] = v;
        s += v * v;
      }
      s += __shfl_xor(s, 1, 64);
      s += __shfl_xor(s, 2, 64);
      s += __shfl_xor(s, 4, 64);
      s += __shfl_xor(s, 8, 64);
      if ((lane & 15) == 0) part[i][wn] = s;
    }
  }
  __syncthreads();
  if (tid < CHUNK) rs_l[tid] = rsqrtf((part[tid][0] + part[tid][1]) * (1.0f / HD) + EPSF);
  __syncthreads();

  // --- gate + store ---
#pragma unroll
  for (int mi = 0; mi < 4; ++mi) {
#pragma unroll
    for (int r = 0; r < 4; ++r) {
      int i = wm * 64 + mi * 16 + (lane >> 4) * 4 + r;
      long row = rowbase + i;
      float rs = rs_l[i];
#pragma unroll
      for (int ni = 0; ni < 2; ++ni) {
        int p = wn * 32 + ni * 16 + (lane & 15);
        float gval = (float)proj[row * NPADN + CONVD + h * HD + p];
        float val = yv[mi][ni][r] * rs * gnw[p] * fsilu(gval);
        yg[row * (long)DMODEL + h * HD + p] = (bf16)val;
      }
    }
  }
}

// ---------------- launch ----------------
extern "C" void kernel_launch(void* const* d_in, const int* in_sizes, int n_in,
                              void* d_out, int out_size, void* d_ws, size_t ws_size,
                              hipStream_t stream) {
  const float* hs      = (const float*)d_in[0];
  const float* W1      = (const float*)d_in[1];
  const float* conv_w  = (const float*)d_in[2];
  const float* conv_b  = (const float*)d_in[3];
  const float* dt_bias = (const float*)d_in[4];
  const float* A_log   = (const float*)d_in[5];
  const float* gnw     = (const float*)d_in[6];
  const float* Wo      = (const float*)d_in[7];

  char* p = (char*)d_ws;
  bf16* hs_b   = (bf16*)p;  p += (long)ROWS * DMODEL * 2;
  bf16* w1_b   = (bf16*)p;  p += (long)NPADN * DMODEL * 2;
  bf16* wo_b   = (bf16*)p;  p += (long)DMODEL * DMODEL * 2;
  bf16* proj   = (bf16*)p;  p += (long)ROWS * NPADN * 2;
  float* st    = (float*)p; p += (long)NB * NCHUNK * NH * HD * HD * 4;
  float* sprev = (float*)p; p += (long)NB * NCHUNK * NH * HD * HD * 4;
  float* asum  = (float*)p; p += (long)NB * NH * NCHUNK * 4;
  bf16* yg     = (bf16*)p;  p += (long)ROWS * DMODEL * 2;

  cast_all_kernel<<<4096, 256, 0, stream>>>(hs, W1, Wo, hs_b, w1_b, wo_b);

  gemm_bt_kernel<bf16><<<(ROWS / 128) * (NPADN / 128), 256, 0, stream>>>(
      hs_b, w1_b, proj, ROWS, NPADN, DMODEL, NPADN / 128);

  ssd_states_kernel<<<NB * NCHUNK * NH, 256, 0, stream>>>(
      proj, conv_w, conv_b, dt_bias, A_log, st, asum);
  ssd_scan_kernel<<<NB * NH * 8, 256, 0, stream>>>(st, asum, sprev);
  ssd_out_kernel<<<NB * NCHUNK * NH, 256, 0, stream>>>(
      proj, conv_w, conv_b, dt_bias, A_log, sprev, gnw, yg);

  gemm_bt_kernel<float><<<(ROWS / 128) * (DMODEL / 128), 256, 0, stream>>>(
      yg, wo_b, (float*)d_out, ROWS, DMODEL, DMODEL, DMODEL / 128);
}

// Round 5
// 383.379 us; speedup vs baseline: 1.2076x; 1.2076x over previous
//
#include <hip/hip_runtime.h>
#include <hip/hip_bf16.h>
#include <math.h>

typedef __bf16 bf16;
typedef __bf16 bf16x4 __attribute__((ext_vector_type(4)));
typedef __bf16 bf16x8 __attribute__((ext_vector_type(8)));
typedef float f32x4 __attribute__((ext_vector_type(4)));

#define NB 2
#define LSEQ 2048
#define NH 32
#define NKVH 8
#define HD 64
#define DMODEL 2048
#define CONVD 3072
#define NPROJ 5152
#define NPADN 5248
#define NCHUNK 16
#define CHUNK 128
#define ROWS 4096
#define EPSF 1e-5f

__device__ __forceinline__ float fsilu(float x) { return x / (1.0f + __expf(-x)); }
__device__ __forceinline__ float fsoftplus(float raw) {
  return (raw > 20.0f) ? raw : log1pf(__expf(raw));
}

__device__ __forceinline__ void gld_lds16(const void* g, void* l) {
  __builtin_amdgcn_global_load_lds(
      (const __attribute__((address_space(1))) void*)g,
      (__attribute__((address_space(3))) void*)l, 16, 0, 0);
}

// xor-chunk swizzle address maps (LDS side). Global tiles are plain row-major;
// the DMA staging permutes the per-lane SOURCE chunk so the LDS image matches.
__device__ __forceinline__ int swz64(int row, int col) {
  return row * 64 + ((((col >> 3) ^ row) & 7) << 3) + (col & 7);
}
__device__ __forceinline__ int swz128(int row, int col) {
  return row * 128 + (((col >> 3) ^ (row & 7)) << 3) + (col & 7);
}

// stage a row-major tile with 64 cols (bf16) into LDS with xor-chunk swizzle
__device__ __forceinline__ void stage64(const bf16* gsrc, bf16* lds, int tid, int nelem) {
  for (int i0 = 0; i0 < nelem; i0 += 2048) {
    int e = i0 + tid * 8;
    int row = e >> 6;
    int sc = ((tid & 7) ^ (row & 7)) << 3;
    gld_lds16((const void*)(gsrc + (row << 6) + sc), (void*)(lds + e));
  }
}
// 128-col variant
__device__ __forceinline__ void stage128(const bf16* gsrc, bf16* lds, int tid, int nelem) {
  for (int i0 = 0; i0 < nelem; i0 += 2048) {
    int e = i0 + tid * 8;
    int row = e >> 7;
    int sc = (((tid & 15) ^ (row & 7))) << 3;
    gld_lds16((const void*)(gsrc + (row << 7) + sc), (void*)(lds + e));
  }
}

// barrier-free inclusive scan of 128 values (each wave redundantly): a0=scan[lane], a1=scan[64+lane]
__device__ __forceinline__ void wave_scan128(float& a0, float& a1, int lane) {
#pragma unroll
  for (int off = 1; off < 64; off <<= 1) {
    float t0 = __shfl_up(a0, off);
    float t1 = __shfl_up(a1, off);
    if (lane >= off) { a0 += t0; a1 += t1; }
  }
  a1 += __shfl(a0, 63);
}

// ---------------- fused casts: hs, W1 (zero-padded to NPADN rows), Wo ----------------
__global__ __launch_bounds__(256) void cast_all_kernel(
    const float* __restrict__ hs, const float* __restrict__ w1, const float* __restrict__ wo,
    bf16* __restrict__ hs_b, bf16* __restrict__ w1_b, bf16* __restrict__ wo_b) {
  const long n1 = (long)ROWS * DMODEL / 4;
  const long n2 = (long)NPADN * DMODEL / 4;
  const long n3 = (long)DMODEL * DMODEL / 4;
  long total = n1 + n2 + n3;
  long stride = (long)gridDim.x * blockDim.x;
  for (long i = blockIdx.x * (long)blockDim.x + threadIdx.x; i < total; i += stride) {
    if (i < n1) {
      float4 v = ((const float4*)hs)[i];
      ((bf16x4*)hs_b)[i] = bf16x4{(bf16)v.x, (bf16)v.y, (bf16)v.z, (bf16)v.w};
    } else if (i < n1 + n2) {
      long j = i - n1;
      int n = (int)((j * 4) >> 11);
      bf16x4 o = {};
      if (n < NPROJ) {
        float4 v = ((const float4*)w1)[j];
        o = bf16x4{(bf16)v.x, (bf16)v.y, (bf16)v.z, (bf16)v.w};
      }
      ((bf16x4*)w1_b)[j] = o;
    } else {
      long j = i - n1 - n2;
      float4 v = ((const float4*)wo)[j];
      ((bf16x4*)wo_b)[j] = bf16x4{(bf16)v.x, (bf16)v.y, (bf16)v.z, (bf16)v.w};
    }
  }
}

// ---------------- GEMM: C[M,N] = A[M,K] * B[N,K]^T ----------------
template <typename OutT>
__global__ __launch_bounds__(256) void gemm_bt_kernel(
    const bf16* __restrict__ A, const bf16* __restrict__ B, OutT* __restrict__ C,
    int M, int N, int K, int ntx) {
  __shared__ __align__(16) bf16 As[128 * 64];
  __shared__ __align__(16) bf16 Bs[128 * 64];
  const int tid = threadIdx.x;
  const int lane = tid & 63;
  const int wave = tid >> 6;
  const int wm = wave >> 1, wn = wave & 1;

  const int GM = 8;
  int lid = blockIdx.x;
  int group = GM * ntx;
  int gid = lid / group;
  int rem = lid - gid * group;
  int bm = gid * GM + (rem % GM);
  int bn = rem / GM;

  f32x4 acc[4][4] = {};

  const bf16* Ab = A + (long)bm * 128 * K;
  const bf16* Bb = B + (long)bn * 128 * K;

  const int colsw = (((lane & 7) ^ ((lane >> 3) & 7)) << 3);
  const int fbA = (wm * 64 + (lane & 15)) * 64 + ((((lane >> 4) ^ (lane & 7))) << 3);
  const int fbB = (wn * 64 + (lane & 15)) * 64 + ((((lane >> 4) ^ (lane & 7))) << 3);

  for (int k0 = 0; k0 < K; k0 += 64) {
#pragma unroll
    for (int j = 0; j < 4; ++j) {
      int q = wave * 4 + j;
      int e = q * 512 + lane * 8;
      int row = q * 8 + (lane >> 3);
      gld_lds16((const void*)(Ab + (long)row * K + k0 + colsw), (void*)(As + e));
      gld_lds16((const void*)(Bb + (long)row * K + k0 + colsw), (void*)(Bs + e));
    }
    __syncthreads();
#pragma unroll
    for (int ks2 = 0; ks2 < 2; ++ks2) {
      bf16x8 af[4], bfb[4];
#pragma unroll
      for (int mi = 0; mi < 4; ++mi)
        af[mi] = *(const bf16x8*)(As + ((fbA + mi * 1024) ^ (ks2 << 5)));
#pragma unroll
      for (int ni = 0; ni < 4; ++ni)
        bfb[ni] = *(const bf16x8*)(Bs + ((fbB + ni * 1024) ^ (ks2 << 5)));
#pragma unroll
      for (int mi = 0; mi < 4; ++mi)
#pragma unroll
        for (int ni = 0; ni < 4; ++ni)
          acc[mi][ni] = __builtin_amdgcn_mfma_f32_16x16x32_bf16(af[mi], bfb[ni], acc[mi][ni], 0, 0, 0);
    }
    __syncthreads();
  }

#pragma unroll
  for (int mi = 0; mi < 4; ++mi) {
    int rbase = bm * 128 + wm * 64 + mi * 16 + (lane >> 4) * 4;
#pragma unroll
    for (int ni = 0; ni < 4; ++ni) {
      int col = bn * 128 + wn * 64 + ni * 16 + (lane & 15);
#pragma unroll
      for (int r = 0; r < 4; ++r)
        C[(long)(rbase + r) * N + col] = (OutT)acc[mi][ni][r];
    }
  }
}

// ---------------- prep: conv+SiLU into MFMA-ready tiles + dt ----------------
// blocks 0..1023:   Q  (b,c,h)  -> Qc[(b,c,h)][i][n]        (row-major 128x64)
// blocks 1024..1279: K (b,c,kvh)-> Kc[j][n] and Kt[n][j]
// blocks 1280..1535: V (b,c,kvh)-> Vt[p][j]
// blocks 1536..1567: D (b,c)    -> dtb/adtb[(b,c,h)][j]
__global__ __launch_bounds__(256) void prep_kernel(
    const bf16* __restrict__ proj, const float* __restrict__ conv_w,
    const float* __restrict__ conv_b, const float* __restrict__ dt_bias,
    const float* __restrict__ A_log,
    bf16* __restrict__ Qc, bf16* __restrict__ Kc, bf16* __restrict__ Kt,
    bf16* __restrict__ Vt, float* __restrict__ dtb, float* __restrict__ adtb) {
  __shared__ float tile[128][65];
  int blk = blockIdx.x, tid = threadIdx.x;

  if (blk < 1024) {
    int h = blk & 31, c = (blk >> 5) & 15, b = blk >> 9;
    long rowbase = (long)b * LSEQ + c * CHUNK;
    int j = tid >> 1, p0 = (tid & 1) * 32;
    const bf16* cur = proj + (rowbase + j) * NPADN;
    bool hp = (c > 0) || (j > 0);
    int chb = 1024 + h * 64;
    bf16* outb = Qc + (long)blk * 8192 + j * 64;
#pragma unroll
    for (int pp = 0; pp < 32; pp += 4) {
      int p = p0 + pp, ch = chb + p;
      bf16x4 cu = *(const bf16x4*)(cur + ch);
      bf16x4 pv = {};
      if (hp) pv = *(const bf16x4*)(cur + ch - NPADN);
      float4 wa = *(const float4*)(conv_w + 2 * ch);
      float4 wb = *(const float4*)(conv_w + 2 * ch + 4);
      float4 bb = *(const float4*)(conv_b + ch);
      bf16x4 o;
      o[0] = (bf16)fsilu((float)pv[0] * wa.x + (float)cu[0] * wa.y + bb.x);
      o[1] = (bf16)fsilu((float)pv[1] * wa.z + (float)cu[1] * wa.w + bb.y);
      o[2] = (bf16)fsilu((float)pv[2] * wb.x + (float)cu[2] * wb.y + bb.z);
      o[3] = (bf16)fsilu((float)pv[3] * wb.z + (float)cu[3] * wb.w + bb.w);
      *(bf16x4*)(outb + p) = o;
    }
  } else if (blk < 1536) {
    int r = blk - 1024;
    bool isK = r < 256;
    int rr = isK ? r : r - 256;
    int kvh = rr & 7, c = (rr >> 3) & 15, b = rr >> 7;
    long rowbase = (long)b * LSEQ + c * CHUNK;
    int chb = (isK ? 512 : 0) + kvh * 64;
    int j = tid >> 1, p0 = (tid & 1) * 32;
    const bf16* cur = proj + (rowbase + j) * NPADN;
    bool hp = (c > 0) || (j > 0);
#pragma unroll
    for (int pp = 0; pp < 32; pp += 4) {
      int p = p0 + pp, ch = chb + p;
      bf16x4 cu = *(const bf16x4*)(cur + ch);
      bf16x4 pv = {};
      if (hp) pv = *(const bf16x4*)(cur + ch - NPADN);
      float4 wa = *(const float4*)(conv_w + 2 * ch);
      float4 wb = *(const float4*)(conv_w + 2 * ch + 4);
      float4 bb = *(const float4*)(conv_b + ch);
      tile[j][p + 0] = fsilu((float)pv[0] * wa.x + (float)cu[0] * wa.y + bb.x);
      tile[j][p + 1] = fsilu((float)pv[1] * wa.z + (float)cu[1] * wa.w + bb.y);
      tile[j][p + 2] = fsilu((float)pv[2] * wb.x + (float)cu[2] * wb.y + bb.z);
      tile[j][p + 3] = fsilu((float)pv[3] * wb.z + (float)cu[3] * wb.w + bb.w);
    }
    __syncthreads();
    long tb = (long)rr * 8192;
    if (isK) {
#pragma unroll
      for (int it = 0; it < 8; ++it) {
        int e = it * 1024 + tid * 4;
        int jj = e >> 6, n = e & 63;
        bf16x4 o = {(bf16)tile[jj][n], (bf16)tile[jj][n + 1], (bf16)tile[jj][n + 2], (bf16)tile[jj][n + 3]};
        *(bf16x4*)(Kc + tb + e) = o;
      }
#pragma unroll
      for (int it = 0; it < 8; ++it) {
        int e = it * 1024 + tid * 4;
        int n = e >> 7, jj = e & 127;
        bf16x4 o = {(bf16)tile[jj][n], (bf16)tile[jj + 1][n], (bf16)tile[jj + 2][n], (bf16)tile[jj + 3][n]};
        *(bf16x4*)(Kt + tb + e) = o;
      }
    } else {
#pragma unroll
      for (int it = 0; it < 8; ++it) {
        int e = it * 1024 + tid * 4;
        int n = e >> 7, jj = e & 127;
        bf16x4 o = {(bf16)tile[jj][n], (bf16)tile[jj + 1][n], (bf16)tile[jj + 2][n], (bf16)tile[jj + 3][n]};
        *(bf16x4*)(Vt + tb + e) = o;
      }
    }
  } else {
    int r = blk - 1536;
    int c = r & 15, b = r >> 4;
    long rowbase = (long)b * LSEQ + c * CHUNK;
    int j = tid >> 1, h0 = (tid & 1) * 16;
    const bf16* dr = proj + (rowbase + j) * NPADN + (CONVD + DMODEL);
    int obase = (b * 16 + c) * 32;
#pragma unroll
    for (int u = 0; u < 16; ++u) {
      int h = h0 + u;
      float raw = (float)dr[h] + dt_bias[h];
      float dtv = fsoftplus(raw);
      dtb[(long)(obase + h) * 128 + j] = dtv;
      adtb[(long)(obase + h) * 128 + j] = -__expf(A_log[h]) * dtv;
    }
  }
}

// ---------------- SSD phase A: S[p][n] = sum_j Vt[p][j] * (Kt[n][j]*w[j]) ----------------
__global__ __launch_bounds__(256) void ssd_states_kernel(
    const bf16* __restrict__ Kt, const bf16* __restrict__ Vt,
    const float* __restrict__ dtb, const float* __restrict__ adtb,
    float* __restrict__ states, float* __restrict__ asum) {
  __shared__ __align__(16) bf16 Vs[64 * 128];
  __shared__ __align__(16) bf16 Ks[64 * 128];
  __shared__ float w[CHUNK];
  int bid = blockIdx.x;                       // ((b*16+c)*32+h)
  int h = bid & 31, c = (bid >> 5) & 15, b = bid >> 9;
  int kvh = h >> 2;
  int tid = threadIdx.x;
  int lane = tid & 63, wave = tid >> 6;
  long kvb = (long)(((b * 16 + c) * 8) + kvh) * 8192;

  stage128(Vt + kvb, Vs, tid, 8192);
  stage128(Kt + kvb, Ks, tid, 8192);

  float a0 = adtb[(long)bid * 128 + lane];
  float a1 = adtb[(long)bid * 128 + 64 + lane];
  float d0 = dtb[(long)bid * 128 + lane];
  float d1 = dtb[(long)bid * 128 + 64 + lane];
  wave_scan128(a0, a1, lane);
  float atot = __shfl(a1, 63);
  if (wave == 0) {
    w[lane] = d0 * __expf(atot - a0);
    w[64 + lane] = d1 * __expf(atot - a1);
  }
  __syncthreads();

  // in-place scale Ks by w[j]
#pragma unroll
  for (int it = 0; it < 4; ++it) {
    int e = it * 2048 + tid * 8;
    int row = e >> 7;
    int j0 = (((tid & 15) ^ (row & 7))) << 3;
    f32x4 wa = *(const f32x4*)(w + j0);
    f32x4 wb = *(const f32x4*)(w + j0 + 4);
    bf16x8 kv = *(const bf16x8*)(Ks + e);
    kv[0] = (bf16)((float)kv[0] * wa[0]); kv[1] = (bf16)((float)kv[1] * wa[1]);
    kv[2] = (bf16)((float)kv[2] * wa[2]); kv[3] = (bf16)((float)kv[3] * wa[3]);
    kv[4] = (bf16)((float)kv[4] * wb[0]); kv[5] = (bf16)((float)kv[5] * wb[1]);
    kv[6] = (bf16)((float)kv[6] * wb[2]); kv[7] = (bf16)((float)kv[7] * wb[3]);
    *(bf16x8*)(Ks + e) = kv;
  }
  __syncthreads();

  f32x4 sacc[4] = {};
#pragma unroll
  for (int ks = 0; ks < CHUNK; ks += 32) {
    bf16x8 af = *(const bf16x8*)(Vs + swz128(wave * 16 + (lane & 15), ks + (lane >> 4) * 8));
    bf16x8 bf_[4];
#pragma unroll
    for (int ni = 0; ni < 4; ++ni)
      bf_[ni] = *(const bf16x8*)(Ks + swz128(ni * 16 + (lane & 15), ks + (lane >> 4) * 8));
#pragma unroll
    for (int ni = 0; ni < 4; ++ni)
      sacc[ni] = __builtin_amdgcn_mfma_f32_16x16x32_bf16(af, bf_[ni], sacc[ni], 0, 0, 0);
  }
  float* sout = states + (long)bid * (HD * HD);
#pragma unroll
  for (int ni = 0; ni < 4; ++ni) {
    int n = ni * 16 + (lane & 15);
#pragma unroll
    for (int r = 0; r < 4; ++r) {
      int p = wave * 16 + (lane >> 4) * 4 + r;
      sout[p * HD + n] = sacc[ni][r];
    }
  }
  if (tid == 0) asum[(b * NH + h) * NCHUNK + c] = atot;
}

// ---------------- SSD phase B: inter-chunk state scan (bf16 out) ----------------
__global__ __launch_bounds__(256) void ssd_scan_kernel(
    const float* __restrict__ states, const float* __restrict__ asum,
    bf16* __restrict__ sprevb) {
  int bid = blockIdx.x;                       // b*256 + h*8 + s
  int s = bid & 7, h = (bid >> 3) & 31, b = bid >> 8;
  int e0 = s * 512 + threadIdx.x;
  int e1 = e0 + 256;
  float S0 = 0.f, S1 = 0.f;
  const float* as = asum + (b * NH + h) * NCHUNK;
  for (int c = 0; c < NCHUNK; ++c) {
    long off = ((long)((b * NCHUNK + c) * NH + h)) * (HD * HD);
    float g = __expf(as[c]);
    sprevb[off + e0] = (bf16)S0;
    sprevb[off + e1] = (bf16)S1;
    S0 = S0 * g + states[off + e0];
    S1 = S1 * g + states[off + e1];
  }
}

// ---------------- SSD phase C: G=Qc.Kc^T -> Yd=G'.Vt^T, Yo=Qc.Sp^T, RMSNorm+gate ----------------
__global__ __launch_bounds__(256) void ssd_out_kernel(
    const bf16* __restrict__ Qc, const bf16* __restrict__ Kc, const bf16* __restrict__ Vt,
    const bf16* __restrict__ sprevb, const float* __restrict__ dtb,
    const float* __restrict__ adtb, const bf16* __restrict__ proj,
    const float* __restrict__ gnw, bf16* __restrict__ yg) {
  __shared__ __align__(16) bf16 Qs[128 * 64];
  __shared__ __align__(16) bf16 KVs[128 * 64];  // Kc -> Vt -> gate
  __shared__ __align__(16) bf16 G[128 * 128];
  __shared__ __align__(16) bf16 Sps[64 * 64];
  __shared__ float acs[CHUNK];
  __shared__ float dts[CHUNK];
  __shared__ float part[CHUNK][2];
  __shared__ float rs_l[CHUNK];

  int bid = blockIdx.x;                       // ((b*16+c)*32+h)
  int h = bid & 31, c = (bid >> 5) & 15, b = bid >> 9;
  int kvh = h >> 2;
  int tid = threadIdx.x;
  int lane = tid & 63, wave = tid >> 6;
  int wm = wave >> 1, wn = wave & 1;
  long rowbase = (long)b * LSEQ + c * CHUNK;
  long kvb = (long)(((b * 16 + c) * 8) + kvh) * 8192;

  stage64(Qc + (long)bid * 8192, Qs, tid, 8192);
  stage64(Kc + kvb, KVs, tid, 8192);
  stage64(sprevb + (long)bid * 4096, Sps, tid, 4096);

  float a0 = adtb[(long)bid * 128 + lane];
  float a1 = adtb[(long)bid * 128 + 64 + lane];
  float d0 = dtb[(long)bid * 128 + lane];
  float d1 = dtb[(long)bid * 128 + 64 + lane];
  wave_scan128(a0, a1, lane);
  if (wave == 0) {
    acs[lane] = a0; acs[64 + lane] = a1;
    dts[lane] = d0; dts[64 + lane] = d1;
  }
  __syncthreads();   // DMA drained + scan visible

  // --- G = Qs . Kc^T (128x128, K=64), then mask * exp(ai-aj) * dt[j] ---
  {
    f32x4 gacc[4][4] = {};
#pragma unroll
    for (int ks = 0; ks < HD; ks += 32) {
      bf16x8 af[4], bf_[4];
#pragma unroll
      for (int mi = 0; mi < 4; ++mi)
        af[mi] = *(const bf16x8*)(Qs + swz64(wm * 64 + mi * 16 + (lane & 15), ks + (lane >> 4) * 8));
#pragma unroll
      for (int ni = 0; ni < 4; ++ni)
        bf_[ni] = *(const bf16x8*)(KVs + swz64(wn * 64 + ni * 16 + (lane & 15), ks + (lane >> 4) * 8));
#pragma unroll
      for (int mi = 0; mi < 4; ++mi)
#pragma unroll
        for (int ni = 0; ni < 4; ++ni)
          gacc[mi][ni] = __builtin_amdgcn_mfma_f32_16x16x32_bf16(af[mi], bf_[ni], gacc[mi][ni], 0, 0, 0);
    }
    float aj[4], dj[4];
#pragma unroll
    for (int ni = 0; ni < 4; ++ni) {
      int j = wn * 64 + ni * 16 + (lane & 15);
      aj[ni] = acs[j];
      dj[ni] = dts[j];
    }
#pragma unroll
    for (int mi = 0; mi < 4; ++mi) {
#pragma unroll
      for (int r = 0; r < 4; ++r) {
        int i = wm * 64 + mi * 16 + (lane >> 4) * 4 + r;
        float ai = acs[i];
#pragma unroll
        for (int ni = 0; ni < 4; ++ni) {
          int j = wn * 64 + ni * 16 + (lane & 15);
          float gv = (j <= i) ? gacc[mi][ni][r] * __expf(ai - aj[ni]) * dj[ni] : 0.f;
          G[swz128(i, j)] = (bf16)gv;
        }
      }
    }
  }
  __syncthreads();   // all waves done reading Kc; G written

  stage128(Vt + kvb, KVs, tid, 8192);   // overwrite KVs with Vt
  __syncthreads();   // DMA drained

  // --- Yd = G . Vt^T (K=128); Yo = Qs . Sp^T (K=64) ---
  f32x4 yacc[4][2] = {};
  f32x4 oacc[4][2] = {};
#pragma unroll
  for (int ks = 0; ks < CHUNK; ks += 32) {
    bf16x8 af[4], bf_[2];
#pragma unroll
    for (int mi = 0; mi < 4; ++mi)
      af[mi] = *(const bf16x8*)(G + swz128(wm * 64 + mi * 16 + (lane & 15), ks + (lane >> 4) * 8));
#pragma unroll
    for (int ni = 0; ni < 2; ++ni)
      bf_[ni] = *(const bf16x8*)(KVs + swz128(wn * 32 + ni * 16 + (lane & 15), ks + (lane >> 4) * 8));
#pragma unroll
    for (int mi = 0; mi < 4; ++mi)
#pragma unroll
      for (int ni = 0; ni < 2; ++ni)
        yacc[mi][ni] = __builtin_amdgcn_mfma_f32_16x16x32_bf16(af[mi], bf_[ni], yacc[mi][ni], 0, 0, 0);
  }
#pragma unroll
  for (int ks = 0; ks < HD; ks += 32) {
    bf16x8 af[4], bf_[2];
#pragma unroll
    for (int mi = 0; mi < 4; ++mi)
      af[mi] = *(const bf16x8*)(Qs + swz64(wm * 64 + mi * 16 + (lane & 15), ks + (lane >> 4) * 8));
#pragma unroll
    for (int ni = 0; ni < 2; ++ni)
      bf_[ni] = *(const bf16x8*)(Sps + swz64(wn * 32 + ni * 16 + (lane & 15), ks + (lane >> 4) * 8));
#pragma unroll
    for (int mi = 0; mi < 4; ++mi)
#pragma unroll
      for (int ni = 0; ni < 2; ++ni)
        oacc[mi][ni] = __builtin_amdgcn_mfma_f32_16x16x32_bf16(af[mi], bf_[ni], oacc[mi][ni], 0, 0, 0);
  }

  // --- combine + RMSNorm partials ---
  float yv[4][2][4];
#pragma unroll
  for (int mi = 0; mi < 4; ++mi) {
#pragma unroll
    for (int r = 0; r < 4; ++r) {
      int i = wm * 64 + mi * 16 + (lane >> 4) * 4 + r;
      float ei = __expf(acs[i]);
      float s = 0.f;
#pragma unroll
      for (int ni = 0; ni < 2; ++ni) {
        float v = yacc[mi][ni][r] + ei * oacc[mi][ni][r];
        yv[mi][ni][r] = v;
        s += v * v;
      }
      s += __shfl_xor(s, 1, 64);
      s += __shfl_xor(s, 2, 64);
      s += __shfl_xor(s, 4, 64);
      s += __shfl_xor(s, 8, 64);
      if ((lane & 15) == 0) part[i][wn] = s;
    }
  }
  __syncthreads();   // everyone done reading Vt/Sps; part visible

  // stage gate slice (raw proj, no conv) into KVs
  for (int i0 = 0; i0 < 8192; i0 += 2048) {
    int e = i0 + tid * 8;
    int row = e >> 6;
    int sc = ((tid & 7) ^ (row & 7)) << 3;
    gld_lds16((const void*)(proj + (rowbase + row) * NPADN + CONVD + h * 64 + sc),
              (void*)(KVs + e));
  }
  if (tid < CHUNK) rs_l[tid] = rsqrtf((part[tid][0] + part[tid][1]) * (1.0f / HD) + EPSF);
  __syncthreads();   // gate drained + rs visible

  // --- gate + store ---
#pragma unroll
  for (int mi = 0; mi < 4; ++mi) {
#pragma unroll
    for (int r = 0; r < 4; ++r) {
      int i = wm * 64 + mi * 16 + (lane >> 4) * 4 + r;
      long row = rowbase + i;
      float rs = rs_l[i];
#pragma unroll
      for (int ni = 0; ni < 2; ++ni) {
        int p = wn * 32 + ni * 16 + (lane & 15);
        float gval = (float)KVs[swz64(i, p)];
        float val = yv[mi][ni][r] * rs * gnw[p] * fsilu(gval);
        yg[row * (long)DMODEL + h * HD + p] = (bf16)val;
      }
    }
  }
}

// ---------------- launch ----------------
extern "C" void kernel_launch(void* const* d_in, const int* in_sizes, int n_in,
                              void* d_out, int out_size, void* d_ws, size_t ws_size,
                              hipStream_t stream) {
  const float* hs      = (const float*)d_in[0];
  const float* W1      = (const float*)d_in[1];
  const float* conv_w  = (const float*)d_in[2];
  const float* conv_b  = (const float*)d_in[3];
  const float* dt_bias = (const float*)d_in[4];
  const float* A_log   = (const float*)d_in[5];
  const float* gnw     = (const float*)d_in[6];
  const float* Wo      = (const float*)d_in[7];

  char* p = (char*)d_ws;
  bf16* hs_b   = (bf16*)p;  p += (long)ROWS * DMODEL * 2;
  bf16* w1_b   = (bf16*)p;  p += (long)NPADN * DMODEL * 2;
  bf16* wo_b   = (bf16*)p;  p += (long)DMODEL * DMODEL * 2;
  bf16* proj   = (bf16*)p;  p += (long)ROWS * NPADN * 2;
  bf16* Qc     = (bf16*)p;  p += (long)1024 * 8192 * 2;
  bf16* Kc     = (bf16*)p;  p += (long)256 * 8192 * 2;
  bf16* Kt     = (bf16*)p;  p += (long)256 * 8192 * 2;
  bf16* Vt     = (bf16*)p;  p += (long)256 * 8192 * 2;
  float* dtb   = (float*)p; p += (long)ROWS * NH * 4;
  float* adtb  = (float*)p; p += (long)ROWS * NH * 4;
  float* st    = (float*)p; p += (long)NB * NCHUNK * NH * HD * HD * 4;
  bf16* sprevb = (bf16*)p;  p += (long)NB * NCHUNK * NH * HD * HD * 2;
  float* asum  = (float*)p; p += (long)NB * NH * NCHUNK * 4;
  bf16* yg     = (bf16*)p;  p += (long)ROWS * DMODEL * 2;

  cast_all_kernel<<<4096, 256, 0, stream>>>(hs, W1, Wo, hs_b, w1_b, wo_b);

  gemm_bt_kernel<bf16><<<(ROWS / 128) * (NPADN / 128), 256, 0, stream>>>(
      hs_b, w1_b, proj, ROWS, NPADN, DMODEL, NPADN / 128);

  prep_kernel<<<1568, 256, 0, stream>>>(proj, conv_w, conv_b, dt_bias, A_log,
                                        Qc, Kc, Kt, Vt, dtb, adtb);

  ssd_states_kernel<<<NB * NCHUNK * NH, 256, 0, stream>>>(Kt, Vt, dtb, adtb, st, asum);
  ssd_scan_kernel<<<NB * NH * 8, 256, 0, stream>>>(st, asum, sprevb);
  ssd_out_kernel<<<NB * NCHUNK * NH, 256, 0, stream>>>(
      Qc, Kc, Vt, sprevb, dtb, adtb, proj, gnw, yg);

  gemm_bt_kernel<float><<<(ROWS / 128) * (DMODEL / 128), 256, 0, stream>>>(
      yg, wo_b, (float*)d_out, ROWS, DMODEL, DMODEL, DMODEL / 128);
}